// Round 11
// baseline (113.959 us; speedup 1.0000x reference)
//
#include <hip/hip_runtime.h>
#include <math.h>

#define NUM_GRAPHS 512
#define D 128
#define HDIM 256
#define K 8            // sub-blocks per graph in segment-sum
#define GPB 4          // graphs per block in MLP kernel (4 -> 48 MB wt traffic)
#define B0 64          // blocks in bounds kernel

// workspace layout (ws_size = 256 MiB per R7 fill counters):
//   [0, 2052)          bounds[513] ints
//   [4096, 4096+2MB)   partials: NUM_GRAPHS*K*D floats

// ---------------------------------------------------------------------------
// O(1) int32-vs-int64 detection for the sorted batch array.
// Let j be the largest odd index < N. In an int64 little-endian view, word j
// is the HIGH word of an element -> always 0 (values < 2^31). In int32, word
// j is a late batch value -> nonzero for this sorted 512-graph dataset.
// ---------------------------------------------------------------------------
__device__ __forceinline__ int detect_is64(const int* __restrict__ b, int N)
{
    const int j = ((N - 1) & 1) ? (N - 1) : (N - 2);
    return b[j] == 0;
}

// ---------------------------------------------------------------------------
// Kernel 0: parallel transition scan -> bounds[513] with lower_bound
// semantics (bounds[t] = first i with batch[i] >= t; bounds[512] = N).
// Covers empty graphs. Each transition (a -> b at index i) writes (a,b].
// Amortizes dtype-detect + boundary search ONCE for all downstream blocks
// (per-block binary search cost R9 +5.8 us -- keep this dispatch).
// ---------------------------------------------------------------------------
__global__ __launch_bounds__(256) void bounds_scan(
    const int* __restrict__ batch32, int* __restrict__ bounds, int N)
{
    const int tid  = threadIdx.x;
    const int is64 = detect_is64(batch32, N);
    const long long* batch64 = (const long long*)batch32;

    const int threads = B0 * 256;
    const int per = (N + threads - 1) / threads;
    const int gt  = blockIdx.x * 256 + tid;
    const int i0  = gt * per;
    const int i1  = min(i0 + per, N);

    for (int i = i0; i < i1; ++i) {
        int b = is64 ? (int)batch64[i] : batch32[i];
        if (i == 0) {
            for (int t = 0; t <= b; ++t) bounds[t] = 0;
        } else {
            int a = is64 ? (int)batch64[i - 1] : batch32[i - 1];
            for (int t = a + 1; t <= b; ++t) bounds[t] = i;
        }
        if (i == N - 1) {
            for (int t = b + 1; t <= NUM_GRAPHS; ++t) bounds[t] = N;
        }
    }
}

// ---------------------------------------------------------------------------
// Kernel 1: segment-sum of x into per-(graph, sub-block) partials.
// Grid = NUM_GRAPHS * K = 4096 blocks; per-block overhead is just two scalar
// bound loads. 2-wide unrolled accumulator loop keeps two independent float4
// loads in flight. Every block writes its partial unconditionally (zeros if
// empty) so no workspace zero-init is needed.
// ---------------------------------------------------------------------------
__global__ __launch_bounds__(256) void seg_sum(
    const float* __restrict__ x, const int* __restrict__ bounds,
    float4* __restrict__ partial4)
{
    const int blk = blockIdx.x;
    const int g   = blk >> 3;       // K == 8
    const int k   = blk & 7;
    const int tid = threadIdx.x;

    __shared__ float4 part[256];

    const int start = bounds[g];
    const int end   = bounds[g + 1];
    const int n   = end - start;
    const int per = (n + K - 1) / K;
    const int r0  = start + k * per;
    const int r1  = min(r0 + per, end);

    const int r  = tid >> 5;     // 0..7 row group
    const int c4 = tid & 31;     // float4 column
    float4 a0 = make_float4(0.f, 0.f, 0.f, 0.f);
    float4 a1 = make_float4(0.f, 0.f, 0.f, 0.f);
    const float4* x4 = (const float4*)x;
    int row = r0 + r;
    for (; row + 8 < r1; row += 16) {
        float4 v0 = x4[row * 32 + c4];
        float4 v1 = x4[(row + 8) * 32 + c4];
        a0.x += v0.x; a0.y += v0.y; a0.z += v0.z; a0.w += v0.w;
        a1.x += v1.x; a1.y += v1.y; a1.z += v1.z; a1.w += v1.w;
    }
    if (row < r1) {
        float4 v0 = x4[row * 32 + c4];
        a0.x += v0.x; a0.y += v0.y; a0.z += v0.z; a0.w += v0.w;
    }
    a0.x += a1.x; a0.y += a1.y; a0.z += a1.z; a0.w += a1.w;

    part[tid] = a0;
    __syncthreads();
    for (int s = 4; s >= 1; s >>= 1) {
        if (r < s) {
            float4 o = part[tid + s * 32];
            float4 m = part[tid];
            m.x += o.x; m.y += o.y; m.z += o.z; m.w += o.w;
            part[tid] = m;
        }
        __syncthreads();
    }
    if (tid < 32)
        partial4[blk * 32 + tid] = part[tid];   // coalesced 512B store
}

// ---------------------------------------------------------------------------
// Kernel 2: per-graph MLP + fused scatter. GPB=4 graphs per block -> 128
// blocks; W1/W2 read once per block and reused 4x from registers (weight L2
// traffic 96 -> 48 MB vs GPB=2). Unroll-16 weight loops keep 16 loads in
// flight. Output scatter is one contiguous coalesced sweep over the 4
// adjacent graph spans.
// ---------------------------------------------------------------------------
__global__ __launch_bounds__(256) void mlp_scatter(
    const float* __restrict__ partial, const int* __restrict__ bounds,
    const float* __restrict__ W1, const float* __restrict__ b1,
    const float* __restrict__ W2, const float* __restrict__ b2,
    const float* __restrict__ Wc, const float* __restrict__ bc,
    float* __restrict__ out)
{
    const int g0  = blockIdx.x * GPB;
    const int tid = threadIdx.x;

    __shared__ int   sBound[GPB + 1];
    __shared__ float sS[GPB][D];
    __shared__ float sH[GPB][HDIM];
    __shared__ float sRed[4][GPB];
    __shared__ float sCval[GPB];

    if (tid <= GPB) sBound[tid] = bounds[g0 + tid];

    // reduce K partials -> per-graph sums (256 threads cover 4x128 slots,
    // 2 slots per thread)
    {
        #pragma unroll
        for (int t = 0; t < 2; ++t) {
            const int slot = tid + t * 256;        // 0..511
            const int j    = slot >> 7;            // graph 0..3
            const int dcol = slot & (D - 1);
            float s = 0.f;
            #pragma unroll
            for (int k = 0; k < K; ++k)
                s += partial[((g0 + j) * K + k) * D + dcol];
            sS[j][dcol] = s;
        }
    }
    __syncthreads();

    // layer 1: thread tid owns output column tid, GPB graphs at once
    float a1[GPB];
    {
        float bb = b1[tid];
        #pragma unroll
        for (int j = 0; j < GPB; ++j) a1[j] = bb;
    }
    #pragma unroll 16
    for (int k = 0; k < D; ++k) {
        float w = W1[k * HDIM + tid];
        #pragma unroll
        for (int j = 0; j < GPB; ++j) a1[j] = fmaf(sS[j][k], w, a1[j]);
    }
    #pragma unroll
    for (int j = 0; j < GPB; ++j) {
        float cnt = (float)(sBound[j + 1] - sBound[j]);
        sH[j][tid] = fmaxf(a1[j], 0.f) * cnt;   // agg(h1) = count * h1
    }
    __syncthreads();

    // layer 2 + confidence head
    float a2[GPB];
    {
        float bb = b2[tid];
        #pragma unroll
        for (int j = 0; j < GPB; ++j) a2[j] = bb;
    }
    #pragma unroll 16
    for (int k = 0; k < HDIM; ++k) {
        float w = W2[k * HDIM + tid];
        #pragma unroll
        for (int j = 0; j < GPB; ++j) a2[j] = fmaf(sH[j][k], w, a2[j]);
    }
    float wc = Wc[tid];
    float v[GPB];
    #pragma unroll
    for (int j = 0; j < GPB; ++j) v[j] = fmaxf(a2[j], 0.f) * wc;
    for (int off = 32; off > 0; off >>= 1) {
        #pragma unroll
        for (int j = 0; j < GPB; ++j) v[j] += __shfl_down(v[j], off, 64);
    }
    if ((tid & 63) == 0) {
        #pragma unroll
        for (int j = 0; j < GPB; ++j) sRed[tid >> 6][j] = v[j];
    }
    __syncthreads();
    if (tid < GPB) {
        float cc = sRed[0][tid] + sRed[1][tid] + sRed[2][tid] + sRed[3][tid]
                 + bc[0];
        float m  = fmaxf(cc, 0.f);                       // stable softplus
        float sp = m + log1pf(expf(-fabsf(cc)));
        sCval[tid] = sp / (1.f + sp);
    }
    __syncthreads();

    // contiguous coalesced scatter over the 4 adjacent graph spans
    {
        const int s0 = sBound[0], s1 = sBound[1], s2 = sBound[2],
                  s3 = sBound[3], s4 = sBound[4];
        const float v0 = sCval[0], v1 = sCval[1],
                    v2 = sCval[2], v3 = sCval[3];
        for (int i = s0 + tid; i < s4; i += 256) {
            float val = (i < s1) ? v0 : (i < s2) ? v1 : (i < s3) ? v2 : v3;
            out[i] = val;
        }
    }
}

extern "C" void kernel_launch(void* const* d_in, const int* in_sizes, int n_in,
                              void* d_out, int out_size, void* d_ws, size_t ws_size,
                              hipStream_t stream)
{
    const float* x   = (const float*)d_in[0];
    const int*   bat = (const int*)d_in[1];
    const float* W1  = (const float*)d_in[2];
    const float* b1  = (const float*)d_in[3];
    const float* W2  = (const float*)d_in[4];
    const float* b2  = (const float*)d_in[5];
    const float* Wc  = (const float*)d_in[6];
    const float* bc  = (const float*)d_in[7];
    float* out = (float*)d_out;
    const int N = in_sizes[0] / D;   // 100000

    int*   bounds  = (int*)d_ws;                              // 513 ints
    float* partial = (float*)((char*)d_ws + 4096);            // 2 MB

    bounds_scan<<<B0, 256, 0, stream>>>(bat, bounds, N);
    seg_sum<<<NUM_GRAPHS * K, 256, 0, stream>>>(x, bounds, (float4*)partial);
    mlp_scatter<<<NUM_GRAPHS / GPB, 256, 0, stream>>>(partial, bounds,
                                                      W1, b1, W2, b2, Wc, bc,
                                                      out);
}

// Round 12
// 109.979 us; speedup vs baseline: 1.0362x; 1.0362x over previous
//
#include <hip/hip_runtime.h>
#include <math.h>

#define NUM_GRAPHS 512
#define D 128
#define HDIM 256
#define K 8            // sub-blocks per graph in segment-sum
#define GPB 2          // graphs per block in MLP kernel (R10-best; GPB=4 regressed)

// workspace layout (ws_size = 256 MiB per R7 fill counters):
//   [0, 2052)          bounds[513] ints (written by seg_sum, read by mlp)
//   [4096, 4096+2MB)   partials: NUM_GRAPHS*K*D floats

// ---------------------------------------------------------------------------
// O(1) int32-vs-int64 detection for the sorted batch array.
// Let j be the largest odd index < N. In an int64 little-endian view, word j
// is the HIGH word of an element -> always 0 (values < 2^31). In int32, word
// j is a late batch value -> nonzero for this sorted 512-graph dataset.
// ---------------------------------------------------------------------------
__device__ __forceinline__ int detect_is64(const int* __restrict__ b, int N)
{
    const int j = ((N - 1) & 1) ? (N - 1) : (N - 2);
    return b[j] == 0;
}

// ---------------------------------------------------------------------------
// Wave-parallel 64-ary lower_bound: all 64 lanes probe at once; ballot+popc
// narrows [lo,hi) by 64x per round -> 3 rounds for N=1e5 (vs 17 serial
// dependent loads for binary search -- R9's +5.8us lesson). Latency ~3
// vector loads, overlapped across co-resident blocks.
// Returns first index i with batch[i] >= target (ans valid on ALL lanes'
// lane-0 via readfirstlane pattern; we use lane 0's store).
// ---------------------------------------------------------------------------
__device__ __forceinline__ int wave_lower_bound(const int* __restrict__ b32,
                                                int is64, int N, int target,
                                                int lane)
{
    const long long* b64 = (const long long*)b32;
    int lo = 0, hi = N;
    while (hi > lo) {
        const int len  = hi - lo;
        const int step = (len + 63) >> 6;
        const int p    = lo + lane * step;
        int lt = 0;
        if (p < hi) {
            int v = is64 ? (int)b64[p] : b32[p];
            lt = (v < target);
        }
        unsigned long long m = __ballot(lt);
        int cnt = __popcll(m);
        if (cnt == 0) { hi = lo; break; }          // b[lo] >= target -> ans = lo
        int nlo = lo + (cnt - 1) * step + 1;        // b[nlo-1] < target
        int nhi = min(lo + cnt * step, hi);         // b[nhi] >= target (or ==hi)
        lo = nlo; hi = nhi;                         // shrinks to <= step-1
    }
    return lo;
}

// ---------------------------------------------------------------------------
// Kernel 1: segment-sum of x into per-(graph, sub-block) partials, with
// inline wave-parallel bounds (waves 0/1 find start/end concurrently while
// setup proceeds; ~0.5us, overlapped across 16 blocks/CU). Block k==0 also
// publishes bounds[g] for the MLP kernel (g==511 publishes bounds[512]=N).
// Every block writes its partial unconditionally (zeros if empty).
// ---------------------------------------------------------------------------
__global__ __launch_bounds__(256) void seg_sum(
    const float* __restrict__ x, const int* __restrict__ batch32,
    float4* __restrict__ partial4, int* __restrict__ bounds, int N)
{
    const int blk  = blockIdx.x;
    const int g    = blk >> 3;       // K == 8
    const int k    = blk & 7;
    const int tid  = threadIdx.x;
    const int lane = tid & 63;
    const int wv   = tid >> 6;

    __shared__ int    sStart, sEnd;
    __shared__ float4 part[256];

    if (wv < 2) {
        const int is64 = detect_is64(batch32, N);
        int r = wave_lower_bound(batch32, is64, N, g + wv, lane);
        if (lane == 0) {
            if (wv == 0) sStart = r; else sEnd = r;
        }
    }
    __syncthreads();

    const int start = sStart, end = sEnd;
    if (k == 0 && tid == 0) {
        bounds[g] = start;
        if (g == NUM_GRAPHS - 1) bounds[NUM_GRAPHS] = end;   // == N
    }

    const int n   = end - start;
    const int per = (n + K - 1) / K;
    const int r0  = start + k * per;
    const int r1  = min(r0 + per, end);

    const int r  = tid >> 5;     // 0..7 row group
    const int c4 = tid & 31;     // float4 column
    float4 a0 = make_float4(0.f, 0.f, 0.f, 0.f);
    float4 a1 = make_float4(0.f, 0.f, 0.f, 0.f);
    const float4* x4 = (const float4*)x;
    int row = r0 + r;
    for (; row + 8 < r1; row += 16) {            // 2 loads in flight
        float4 v0 = x4[row * 32 + c4];
        float4 v1 = x4[(row + 8) * 32 + c4];
        a0.x += v0.x; a0.y += v0.y; a0.z += v0.z; a0.w += v0.w;
        a1.x += v1.x; a1.y += v1.y; a1.z += v1.z; a1.w += v1.w;
    }
    if (row < r1) {
        float4 v0 = x4[row * 32 + c4];
        a0.x += v0.x; a0.y += v0.y; a0.z += v0.z; a0.w += v0.w;
    }
    a0.x += a1.x; a0.y += a1.y; a0.z += a1.z; a0.w += a1.w;

    part[tid] = a0;
    __syncthreads();
    for (int s = 4; s >= 1; s >>= 1) {
        if (r < s) {
            float4 o = part[tid + s * 32];
            float4 m = part[tid];
            m.x += o.x; m.y += o.y; m.z += o.z; m.w += o.w;
            part[tid] = m;
        }
        __syncthreads();
    }
    if (tid < 32)
        partial4[blk * 32 + tid] = part[tid];   // coalesced 512B store
}

// ---------------------------------------------------------------------------
// Kernel 2: per-graph MLP + fused scatter (R10-best config, unchanged).
// GPB=2 -> 256 blocks (one per CU), weights reused 2x from registers,
// unroll-16 weight loops. Bounds read directly (published by seg_sum).
// Output scatter is one contiguous coalesced sweep.
// ---------------------------------------------------------------------------
__global__ __launch_bounds__(256) void mlp_scatter(
    const float* __restrict__ partial, const int* __restrict__ bounds,
    const float* __restrict__ W1, const float* __restrict__ b1,
    const float* __restrict__ W2, const float* __restrict__ b2,
    const float* __restrict__ Wc, const float* __restrict__ bc,
    float* __restrict__ out)
{
    const int g0  = blockIdx.x * GPB;
    const int tid = threadIdx.x;

    __shared__ int   sBound[GPB + 1];
    __shared__ float sS[GPB][D];
    __shared__ float sH[GPB][HDIM];
    __shared__ float sRed[4][GPB];
    __shared__ float sCval[GPB];

    if (tid <= GPB) sBound[tid] = bounds[g0 + tid];

    // reduce K partials -> per-graph sums (all 256 threads: j = tid>>7)
    {
        const int j = tid >> 7;        // 0..1
        const int dcol = tid & (D - 1);
        float s = 0.f;
        #pragma unroll
        for (int k = 0; k < K; ++k)
            s += partial[((g0 + j) * K + k) * D + dcol];
        sS[j][dcol] = s;
    }
    __syncthreads();

    // layer 1: thread tid owns output column tid, GPB graphs at once
    float a1[GPB];
    {
        float bb = b1[tid];
        #pragma unroll
        for (int j = 0; j < GPB; ++j) a1[j] = bb;
    }
    #pragma unroll 16
    for (int k = 0; k < D; ++k) {
        float w = W1[k * HDIM + tid];
        #pragma unroll
        for (int j = 0; j < GPB; ++j) a1[j] = fmaf(sS[j][k], w, a1[j]);
    }
    #pragma unroll
    for (int j = 0; j < GPB; ++j) {
        float cnt = (float)(sBound[j + 1] - sBound[j]);
        sH[j][tid] = fmaxf(a1[j], 0.f) * cnt;   // agg(h1) = count * h1
    }
    __syncthreads();

    // layer 2 + confidence head
    float a2[GPB];
    {
        float bb = b2[tid];
        #pragma unroll
        for (int j = 0; j < GPB; ++j) a2[j] = bb;
    }
    #pragma unroll 16
    for (int k = 0; k < HDIM; ++k) {
        float w = W2[k * HDIM + tid];
        #pragma unroll
        for (int j = 0; j < GPB; ++j) a2[j] = fmaf(sH[j][k], w, a2[j]);
    }
    float wc = Wc[tid];
    float v[GPB];
    #pragma unroll
    for (int j = 0; j < GPB; ++j) v[j] = fmaxf(a2[j], 0.f) * wc;
    for (int off = 32; off > 0; off >>= 1) {
        #pragma unroll
        for (int j = 0; j < GPB; ++j) v[j] += __shfl_down(v[j], off, 64);
    }
    if ((tid & 63) == 0) {
        #pragma unroll
        for (int j = 0; j < GPB; ++j) sRed[tid >> 6][j] = v[j];
    }
    __syncthreads();
    if (tid < GPB) {
        float cc = sRed[0][tid] + sRed[1][tid] + sRed[2][tid] + sRed[3][tid]
                 + bc[0];
        float m  = fmaxf(cc, 0.f);                       // stable softplus
        float sp = m + log1pf(expf(-fabsf(cc)));
        sCval[tid] = sp / (1.f + sp);
    }
    __syncthreads();

    // contiguous coalesced scatter over both graphs' adjacent spans
    {
        const int s0 = sBound[0], s1 = sBound[1], s2 = sBound[GPB];
        const float v0 = sCval[0], v1 = sCval[1];
        for (int i = s0 + tid; i < s2; i += 256)
            out[i] = (i < s1) ? v0 : v1;
    }
}

extern "C" void kernel_launch(void* const* d_in, const int* in_sizes, int n_in,
                              void* d_out, int out_size, void* d_ws, size_t ws_size,
                              hipStream_t stream)
{
    const float* x   = (const float*)d_in[0];
    const int*   bat = (const int*)d_in[1];
    const float* W1  = (const float*)d_in[2];
    const float* b1  = (const float*)d_in[3];
    const float* W2  = (const float*)d_in[4];
    const float* b2  = (const float*)d_in[5];
    const float* Wc  = (const float*)d_in[6];
    const float* bc  = (const float*)d_in[7];
    float* out = (float*)d_out;
    const int N = in_sizes[0] / D;   // 100000

    int*   bounds  = (int*)d_ws;                              // 513 ints
    float* partial = (float*)((char*)d_ws + 4096);            // 2 MB

    seg_sum<<<NUM_GRAPHS * K, 256, 0, stream>>>(x, bat, (float4*)partial,
                                                bounds, N);
    mlp_scatter<<<NUM_GRAPHS / GPB, 256, 0, stream>>>(partial, bounds,
                                                      W1, b1, W2, b2, Wc, bc,
                                                      out);
}